// Round 7
// baseline (126.157 us; speedup 1.0000x reference)
//
#include <hip/hip_runtime.h>
#include <hip/hip_bf16.h>

typedef unsigned short u16;
typedef unsigned int u32;
typedef __attribute__((ext_vector_type(4))) float f32x4;
typedef __attribute__((ext_vector_type(8))) short short8;     // 8 bf16 MFMA frag
typedef __attribute__((ext_vector_type(8))) unsigned short u16x8;
typedef __attribute__((ext_vector_type(4))) unsigned short u16x4;
typedef __attribute__((ext_vector_type(2))) unsigned int u32x2;

// B=2, S=2048, E=1024, H=16, HD=64
#define BATCH 2
#define SEQ   2048
#define EMB   1024
#define NH    16
#define HD    64

__device__ inline u16 f2bf(float f) {
    unsigned u = __builtin_bit_cast(unsigned, f);
    unsigned r = u + 0x7FFFu + ((u >> 16) & 1u);   // RNE
    return (u16)(r >> 16);
}

__device__ inline float fexp2(float x) {
    float r;
    asm("v_exp_f32 %0, %1" : "=v"(r) : "v"(x));
    return r;
}

__device__ inline void gload16(const void* g, void* l) {
    __builtin_amdgcn_global_load_lds(
        (const __attribute__((address_space(1))) unsigned int*)g,
        (__attribute__((address_space(3))) unsigned int*)l, 16, 0, 0);
}

// ---------------------------------------------------------------------------
// convert: x (4M f32) -> Xb bf16 ; Wq|Wk|Wv (3M f32) -> Wqkv bf16
// ---------------------------------------------------------------------------
__global__ __launch_bounds__(256) void convert_all(
    const float* __restrict__ x,
    const float* __restrict__ Wq, const float* __restrict__ Wk, const float* __restrict__ Wv,
    u16* __restrict__ Xb, u16* __restrict__ Wqkv)
{
    const long gidx = (long)blockIdx.x * 2048 + (long)threadIdx.x * 8;
    const float* src;
    u16* dst;
    if (gidx < 4194304L) {
        src = x + gidx; dst = Xb + gidx;
    } else {
        const long r = gidx - 4194304L;
        const int w = (int)(r >> 20);
        const long off = r & 1048575L;
        src = (w == 0 ? Wq : w == 1 ? Wk : Wv) + off;
        dst = Wqkv + r;
    }
    f32x4 a = *(const f32x4*)src;
    f32x4 b = *(const f32x4*)(src + 4);
    u16x8 o;
    #pragma unroll
    for (int j = 0; j < 4; ++j) { o[j] = f2bf(a[j]); o[4 + j] = f2bf(b[j]); }
    *(u16x8*)dst = o;
}

__global__ __launch_bounds__(256) void convert_wo(
    const float* __restrict__ Wo, u16* __restrict__ Wob)
{
    const long gidx = (long)blockIdx.x * 2048 + (long)threadIdx.x * 8;
    f32x4 a = *(const f32x4*)(Wo + gidx);
    f32x4 b = *(const f32x4*)(Wo + gidx + 4);
    u16x8 o;
    #pragma unroll
    for (int j = 0; j < 4; ++j) { o[j] = f2bf(a[j]); o[4 + j] = f2bf(b[j]); }
    *(u16x8*)(Wob + gidx) = o;
}

// ---------------------------------------------------------------------------
// gemm256: QKV projection, 256x256 tile, BK=64, 8 waves (2Mx4N), 512 thr.
// Counted vmcnt(8) + raw s_barrier; 2-deep prefetch; XCD-swizzled blockIdx.
// ---------------------------------------------------------------------------
__global__ __launch_bounds__(512, 2) void gemm256(
    const u16* __restrict__ A, const u16* __restrict__ Bb,
    u16* __restrict__ Qo, u16* __restrict__ Ko, u16* __restrict__ VTo)
{
    __shared__ u16 As[2][256 * 64];
    __shared__ u16 Bs[2][256 * 64];

    const int tid = threadIdx.x;
    const int lane = tid & 63;
    const int wid = tid >> 6;          // 0..7
    const int lr = lane & 15;
    const int lg = lane >> 4;
    const int wr = wid >> 2;           // 0..1 -> M offset wr*128
    const int wc = wid & 3;            // 0..3 -> N offset wc*64

    // XCD swizzle: 192 blocks (16 x 12), 24 per XCD, contiguous logical chunk
    const int lin = blockIdx.y * 16 + blockIdx.x;
    const int swz = (lin & 7) * 24 + (lin >> 3);
    const int m0 = (swz & 15) * 256;
    const int n0 = (swz >> 4) * 256;

    const int grow = lane >> 3;
    const int schunk = ((lane & 7) ^ grow) << 4;

    auto issueTile = [&](int kt, int buf) {
        const int k0b = kt * 128;      // byte offset in 2048B K-row
        #pragma unroll
        for (int i = 0; i < 4; ++i) {
            const int row = i * 64 + wid * 8 + grow;
            gload16((const char*)A + (size_t)(m0 + row) * 2048 + k0b + schunk,
                    (char*)As[buf] + i * 8192 + wid * 1024);
            gload16((const char*)Bb + (size_t)(n0 + row) * 2048 + k0b + schunk,
                    (char*)Bs[buf] + i * 8192 + wid * 1024);
        }
    };

    issueTile(0, 0);
    issueTile(1, 1);

    f32x4 acc[8][4] = {};
    const int rsw = (lr & 7);

    for (int t = 0; t < 16; ++t) {
        if (t < 15) { asm volatile("s_waitcnt vmcnt(8)" ::: "memory"); }
        else        { asm volatile("s_waitcnt vmcnt(0)" ::: "memory"); }
        __builtin_amdgcn_sched_barrier(0);
        __builtin_amdgcn_s_barrier();
        __builtin_amdgcn_sched_barrier(0);

        const u16* Ac = As[t & 1];
        const u16* Bc = Bs[t & 1];

        short8 a[4][2], b0[2][2], b1[2][2];

        // ---- phase 1: A-half 0 (fi 0-3) x B-half 0 (fj 0-1) ----
        #pragma unroll
        for (int fi = 0; fi < 4; ++fi)
            #pragma unroll
            for (int ks = 0; ks < 2; ++ks)
                a[fi][ks] = *(const short8*)((const char*)Ac + (wr * 128 + fi * 16 + lr) * 128
                                             + (((ks * 4 + lg) ^ rsw) << 4));
        #pragma unroll
        for (int fj = 0; fj < 2; ++fj)
            #pragma unroll
            for (int ks = 0; ks < 2; ++ks)
                b0[fj][ks] = *(const short8*)((const char*)Bc + (wc * 64 + fj * 16 + lr) * 128
                                              + (((ks * 4 + lg) ^ rsw) << 4));
        __builtin_amdgcn_s_setprio(1);
        #pragma unroll
        for (int fi = 0; fi < 4; ++fi)
            #pragma unroll
            for (int fj = 0; fj < 2; ++fj)
                #pragma unroll
                for (int ks = 0; ks < 2; ++ks)
                    acc[fi][fj] = __builtin_amdgcn_mfma_f32_16x16x32_bf16(a[fi][ks], b0[fj][ks], acc[fi][fj], 0, 0, 0);
        __builtin_amdgcn_s_setprio(0);

        // ---- phase 2: A-half 0 x B-half 1 (fj 2-3) ----
        #pragma unroll
        for (int fj = 0; fj < 2; ++fj)
            #pragma unroll
            for (int ks = 0; ks < 2; ++ks)
                b1[fj][ks] = *(const short8*)((const char*)Bc + (wc * 64 + (fj + 2) * 16 + lr) * 128
                                              + (((ks * 4 + lg) ^ rsw) << 4));
        __builtin_amdgcn_s_setprio(1);
        #pragma unroll
        for (int fi = 0; fi < 4; ++fi)
            #pragma unroll
            for (int fj = 0; fj < 2; ++fj)
                #pragma unroll
                for (int ks = 0; ks < 2; ++ks)
                    acc[fi][fj + 2] = __builtin_amdgcn_mfma_f32_16x16x32_bf16(a[fi][ks], b1[fj][ks], acc[fi][fj + 2], 0, 0, 0);
        __builtin_amdgcn_s_setprio(0);

        // ---- phase 3: A-half 1 (fi 4-7) x B-half 1 ----
        #pragma unroll
        for (int fi = 0; fi < 4; ++fi)
            #pragma unroll
            for (int ks = 0; ks < 2; ++ks)
                a[fi][ks] = *(const short8*)((const char*)Ac + (wr * 128 + (fi + 4) * 16 + lr) * 128
                                             + (((ks * 4 + lg) ^ rsw) << 4));
        __builtin_amdgcn_s_setprio(1);
        #pragma unroll
        for (int fi = 0; fi < 4; ++fi)
            #pragma unroll
            for (int fj = 0; fj < 2; ++fj)
                #pragma unroll
                for (int ks = 0; ks < 2; ++ks)
                    acc[fi + 4][fj + 2] = __builtin_amdgcn_mfma_f32_16x16x32_bf16(a[fi][ks], b1[fj][ks], acc[fi + 4][fj + 2], 0, 0, 0);
        __builtin_amdgcn_s_setprio(0);

        // ---- phase 4: A-half 1 x B-half 0 (no reads) ----
        __builtin_amdgcn_s_setprio(1);
        #pragma unroll
        for (int fi = 0; fi < 4; ++fi)
            #pragma unroll
            for (int fj = 0; fj < 2; ++fj)
                #pragma unroll
                for (int ks = 0; ks < 2; ++ks)
                    acc[fi + 4][fj] = __builtin_amdgcn_mfma_f32_16x16x32_bf16(a[fi][ks], b0[fj][ks], acc[fi + 4][fj], 0, 0, 0);
        __builtin_amdgcn_s_setprio(0);

        __builtin_amdgcn_sched_barrier(0);
        __builtin_amdgcn_s_barrier();
        __builtin_amdgcn_sched_barrier(0);
        if (t + 2 < 16) issueTile(t + 2, t & 1);
    }

    // ---- epilogue: C col = lr (n), row = lg*4 + i (m) ----
    const int w = n0 >> 10;
    const float qs = (w == 0) ? 0.125f * 1.44269504f : 1.0f;
    const int mb = m0 + wr * 128;
    const int nb = n0 + wc * 64;
    #pragma unroll
    for (int fi = 0; fi < 8; ++fi) {
        #pragma unroll
        for (int fj = 0; fj < 4; ++fj) {
            const int m = mb + fi * 16 + lg * 4;
            const int nn = (nb + fj * 16 + lr) & 1023;
            const int h = nn >> 6, d = nn & 63;
            const int bb = m >> 11, s = m & 2047;
            const size_t bh = (size_t)(bb * NH + h);
            if (w == 2) {
                u16x4 v;
                #pragma unroll
                for (int i = 0; i < 4; ++i) v[i] = f2bf(acc[fi][fj][i]);
                *(u16x4*)&VTo[(bh * HD + d) * SEQ + s] = v;
            } else {
                u16* P = (w == 0) ? Qo : Ko;
                #pragma unroll
                for (int i = 0; i < 4; ++i)
                    P[(bh * SEQ + s + i) * HD + d] = f2bf(acc[fi][fj][i] * qs);
            }
        }
    }
}

// ---------------------------------------------------------------------------
// GEMM 128x128, BK=64 — output projection. Counted vmcnt(8) + raw barriers,
// 2-deep prefetch.
// ---------------------------------------------------------------------------
__global__ __launch_bounds__(256) void gemm_out(
    const u16* __restrict__ A, const u16* __restrict__ Bb, float* __restrict__ Fo)
{
    __shared__ u16 As[2][128 * 64];
    __shared__ u16 Bs[2][128 * 64];

    const int tid = threadIdx.x;
    const int m0 = blockIdx.x * 128;
    const int n0 = blockIdx.y * 128;

    const int lane = tid & 63;
    const int lr = lane & 15;
    const int lg = lane >> 4;
    const int wid = tid >> 6;
    const int wm = wid >> 1, wn = wid & 1;

    const int grow = lane >> 3;
    const int gcolb = ((lane & 7) ^ grow) << 4;
    const int rswz = (lr & 7);

    f32x4 acc[4][4] = {};

    auto issue = [&](int kt, int buf) {
        const int k0b = kt * 128;
        #pragma unroll
        for (int t = 0; t < 4; ++t) {
            const int row = (wid * 4 + t) * 8 + grow;
            gload16((const char*)A + (size_t)(m0 + row) * 2048 + k0b + gcolb,
                    (char*)As[buf] + (wid * 4 + t) * 1024);
            gload16((const char*)Bb + (size_t)(n0 + row) * 2048 + k0b + gcolb,
                    (char*)Bs[buf] + (wid * 4 + t) * 1024);
        }
    };

    issue(0, 0);
    issue(1, 1);

    for (int kt = 0; kt < 16; ++kt) {
        if (kt < 15) { asm volatile("s_waitcnt vmcnt(8)" ::: "memory"); }
        else         { asm volatile("s_waitcnt vmcnt(0)" ::: "memory"); }
        __builtin_amdgcn_sched_barrier(0);
        __builtin_amdgcn_s_barrier();
        __builtin_amdgcn_sched_barrier(0);

        const u16* Ac = As[kt & 1];
        const u16* Bc = Bs[kt & 1];
        #pragma unroll
        for (int kk = 0; kk < 2; ++kk) {
            short8 a[4], b[4];
            #pragma unroll
            for (int i = 0; i < 4; ++i)
                a[i] = *(const short8*)((const char*)Ac + (wm * 64 + i * 16 + lr) * 128
                                        + (((kk * 4 + lg) ^ rswz) << 4));
            #pragma unroll
            for (int i = 0; i < 4; ++i)
                b[i] = *(const short8*)((const char*)Bc + (wn * 64 + i * 16 + lr) * 128
                                        + (((kk * 4 + lg) ^ rswz) << 4));
            #pragma unroll
            for (int mi = 0; mi < 4; ++mi)
                #pragma unroll
                for (int ni = 0; ni < 4; ++ni)
                    acc[mi][ni] = __builtin_amdgcn_mfma_f32_16x16x32_bf16(a[mi], b[ni], acc[mi][ni], 0, 0, 0);
        }

        __builtin_amdgcn_sched_barrier(0);
        __builtin_amdgcn_s_barrier();
        __builtin_amdgcn_sched_barrier(0);
        if (kt + 2 < 16) issue(kt + 2, kt & 1);
    }

    const int mb = m0 + wm * 64;
    const int nb = n0 + wn * 64;
    #pragma unroll
    for (int mi = 0; mi < 4; ++mi)
        #pragma unroll
        for (int ni = 0; ni < 4; ++ni) {
            const int m = mb + mi * 16 + lg * 4;
            const int n = nb + ni * 16 + lr;
            #pragma unroll
            for (int i = 0; i < 4; ++i)
                Fo[(size_t)(m + i) * EMB + n] = acc[mi][ni][i];
        }
}

// ---------------------------------------------------------------------------
// Flash attention, swapped-operand, 8 waves x 16 q-rows = 128 q/block.
// T3/T4: 2-deep prefetch, counted vmcnt(2), raw barriers (no implicit drain).
// XCD swizzle: each XCD gets 4 complete bh (K/V L2-resident).
// ---------------------------------------------------------------------------
__global__ __launch_bounds__(512) void attn_fwd(
    const u16* __restrict__ Q, const u16* __restrict__ K,
    const u16* __restrict__ VT, u16* __restrict__ Cat)
{
    __shared__ u16 Ks[2][64 * 64];     // [kv][e], 128B rows, XOR-swizzled
    __shared__ u16 Vs[2][80 * 64];     // [d][kv] rows 0..63; rows 64..79 = 1.0
    __shared__ u16 PT[8][16 * 72];     // per-wave P [q][kv], pad-72

    const int tid = threadIdx.x;
    const int lane = tid & 63;
    const int lr = lane & 15;
    const int lg = lane >> 4;
    const int wid = tid >> 6;

    // XCD swizzle: 512 blocks; XCD c gets logical ids c*64..c*64+63 = bh 4c..4c+3
    const int lin = blockIdx.y * 16 + blockIdx.x;
    const int swz = (lin & 7) * 64 + (lin >> 3);
    const int qt = swz & 15;
    const int bh = swz >> 4;
    const int b = bh >> 4, h = bh & 15;

    if (tid < 128) {
        const int row = 64 + (tid >> 3), sl = tid & 7;
        u16x8 ones;
        #pragma unroll
        for (int j = 0; j < 8; ++j) ones[j] = 0x3F80;
        *(u16x8*)((char*)Vs[0] + row * 128 + ((sl ^ (row & 7)) << 4)) = ones;
        *(u16x8*)((char*)Vs[1] + row * 128 + ((sl ^ (row & 7)) << 4)) = ones;
    }
    asm volatile("s_waitcnt lgkmcnt(0)" ::: "memory");   // ones visible pre-barrier

    const u16* Qg = Q + ((size_t)bh * SEQ + qt * 128 + wid * 16 + lr) * HD;
    short8 qf[2];
    qf[0] = *(const short8*)(Qg + lg * 8);
    qf[1] = *(const short8*)(Qg + 32 + lg * 8);

    float m = -1e30f;
    f32x4 accO[5] = {};

    const u16* Kg = K + (size_t)bh * SEQ * HD;
    const u16* Vg = VT + (size_t)bh * HD * SEQ;

    const int srow = lane >> 3;
    const int schunk = ((lane & 7) ^ srow) << 4;

    auto issueKV = [&](int nt, int buf) {
        const int kv0 = nt * 64;
        const int krow = wid * 8 + srow;
        gload16((const char*)Kg + (size_t)(kv0 + krow) * 128 + schunk,
                (char*)Ks[buf] + wid * 1024);
        gload16((const char*)Vg + (size_t)krow * (SEQ * 2) + kv0 * 2 + schunk,
                (char*)Vs[buf] + wid * 1024);
    };

    issueKV(0, 0);
    issueKV(1, 1);

    const int NT = SEQ / 64;
    for (int nt = 0; nt < NT; ++nt) {
        const int cur = nt & 1;
        if (nt < NT - 1) { asm volatile("s_waitcnt vmcnt(2)" ::: "memory"); }
        else             { asm volatile("s_waitcnt vmcnt(0)" ::: "memory"); }
        __builtin_amdgcn_sched_barrier(0);
        __builtin_amdgcn_s_barrier();
        __builtin_amdgcn_sched_barrier(0);

        // ---- ST = K Q^T : lane owns q=lr; kv = c*16 + lg*4 + i ----
        f32x4 st[4] = {};
        #pragma unroll
        for (int kk = 0; kk < 2; ++kk) {
            const short8 qv = qf[kk];
            #pragma unroll
            for (int c = 0; c < 4; ++c) {
                const short8 kf = *(const short8*)((const char*)Ks[cur] + (c * 16 + lr) * 128
                                                   + (((kk * 4 + lg) ^ (lr & 7)) << 4));
                st[c] = __builtin_amdgcn_mfma_f32_16x16x32_bf16(kf, qv, st[c], 0, 0, 0);
            }
        }

        // ---- online softmax (log2 domain), defer-max ----
        float mx = fmaxf(
            fmaxf(fmaxf(fmaxf(st[0][0], st[0][1]), fmaxf(st[0][2], st[0][3])),
                  fmaxf(fmaxf(st[1][0], st[1][1]), fmaxf(st[1][2], st[1][3]))),
            fmaxf(fmaxf(fmaxf(st[2][0], st[2][1]), fmaxf(st[2][2], st[2][3])),
                  fmaxf(fmaxf(st[3][0], st[3][1]), fmaxf(st[3][2], st[3][3]))));
        mx = fmaxf(mx, __shfl_xor(mx, 16));
        mx = fmaxf(mx, __shfl_xor(mx, 32));
        if (!__all(mx - m <= 11.5f)) {
            const float nm = fmaxf(m, mx);
            const float corr = fexp2(m - nm);
            m = nm;
            #pragma unroll
            for (int dc = 0; dc < 5; ++dc)
                accO[dc] *= corr;
        }
        #pragma unroll
        for (int c = 0; c < 4; ++c)
            #pragma unroll
            for (int i = 0; i < 4; ++i)
                st[c][i] = fexp2(st[c][i] - m);

        // ---- P pack -> PT[q=lr][kv] ----
        #pragma unroll
        for (int c = 0; c < 4; ++c) {
            u32 w0, w1;
            asm("v_cvt_pk_bf16_f32 %0, %1, %2" : "=v"(w0) : "v"(st[c][0]), "v"(st[c][1]));
            asm("v_cvt_pk_bf16_f32 %0, %1, %2" : "=v"(w1) : "v"(st[c][2]), "v"(st[c][3]));
            u32x2 pk; pk[0] = w0; pk[1] = w1;
            *(u32x2*)&PT[wid][lr * 72 + c * 16 + lg * 4] = pk;
        }
        asm volatile("s_waitcnt lgkmcnt(0)" ::: "memory");
        __builtin_amdgcn_sched_barrier(0);

        // ---- O^T += V^T P (dc=4 -> ones rows accumulate l) ----
        #pragma unroll
        for (int kk = 0; kk < 2; ++kk) {
            const short8 pf = *(const short8*)&PT[wid][lr * 72 + kk * 32 + lg * 8];
            #pragma unroll
            for (int dc = 0; dc < 5; ++dc) {
                const short8 vf = *(const short8*)((const char*)Vs[cur] + (dc * 16 + lr) * 128
                                                   + (((kk * 4 + lg) ^ (lr & 7)) << 4));
                accO[dc] = __builtin_amdgcn_mfma_f32_16x16x32_bf16(vf, pf, accO[dc], 0, 0, 0);
            }
        }

        __builtin_amdgcn_sched_barrier(0);
        __builtin_amdgcn_s_barrier();
        __builtin_amdgcn_sched_barrier(0);
        if (nt + 2 < NT) issueKV(nt + 2, cur);
    }

    // ---- epilogue: lane q = lr; d = dc*16 + lg*4 + i ----
    const float invl = 1.f / accO[4][0];
    const int qs = qt * 128 + wid * 16 + lr;
    u16* ob = Cat + (size_t)b * SEQ * EMB + (size_t)qs * EMB + h * HD;
    #pragma unroll
    for (int dc = 0; dc < 4; ++dc) {
        u16x4 o;
        #pragma unroll
        for (int i = 0; i < 4; ++i) o[i] = f2bf(accO[dc][i] * invl);
        *(u16x4*)&ob[dc * 16 + lg * 4] = o;
    }
}

// ---------------------------------------------------------------------------
extern "C" void kernel_launch(void* const* d_in, const int* in_sizes, int n_in,
                              void* d_out, int out_size, void* d_ws, size_t ws_size,
                              hipStream_t stream) {
    const float* x  = (const float*)d_in[0];
    const float* Wq = (const float*)d_in[1];
    const float* Wk = (const float*)d_in[2];
    const float* Wv = (const float*)d_in[3];
    const float* Wo = (const float*)d_in[4];
    float* out = (float*)d_out;

    // d_out (16MB) doubles as bf16 staging for Xb+Wqkv (dead before gemm_out
    // overwrites d_out with the final f32 result).
    u16* Xb   = (u16*)d_out;                          // [4096][1024] bf16
    u16* Wqkv = (u16*)d_out + (size_t)4 * 1048576;    // [3072][1024] bf16

    char* ws = (char*)d_ws;
    u16* Qb  = (u16*)(ws);                            // [B,H,S,64]  8MB
    u16* Kb  = (u16*)(ws + (size_t)8  * 1048576);     // [B,H,S,64]  8MB
    u16* VTb = (u16*)(ws + (size_t)16 * 1048576);     // [B,H,64,S]  8MB
    u16* Cat = (u16*)(ws + (size_t)24 * 1048576);     // [B,S,E]     8MB
    u16* Wob = Qb;                                    // Qb dead after attn

    convert_all<<<3584, 256, 0, stream>>>(x, Wq, Wk, Wv, Xb, Wqkv);

    // QKV projection: M=4096, N=3072, K=1024 (Q pre-scaled by 0.125*log2e)
    dim3 g1(4096 / 256, 3072 / 256);
    gemm256<<<g1, 512, 0, stream>>>(Xb, Wqkv, Qb, Kb, VTb);

    // Attention (128 q-rows/block, 8 waves)
    dim3 g2(SEQ / 128, BATCH * NH);
    attn_fwd<<<g2, 512, 0, stream>>>(Qb, Kb, VTb, Cat);

    // Wo -> bf16 into Qb region, then output projection M=4096,N=1024,K=1024
    convert_wo<<<512, 256, 0, stream>>>(Wo, Wob);
    dim3 g3(4096 / 128, 1024 / 128);
    gemm_out<<<g3, 256, 0, stream>>>(Cat, Wob, out);
}